// Round 3
// baseline (217.060 us; speedup 1.0000x reference)
//
#include <hip/hip_runtime.h>

#define NN 8192
#define DD 256
#define JSPLIT 2
#define JCH (NN / JSPLIT)          // 4096 j's per block
#define NSTEP (JCH / 32)           // 128 K-steps per block

typedef __attribute__((ext_vector_type(8))) short short8;   // 8 bf16 (4 VGPR) MFMA frag
typedef __attribute__((ext_vector_type(4))) float f32x4;    // MFMA accumulator

__device__ __forceinline__ short f2bf(float x) {
    union { float f; unsigned u; } v; v.f = x;
    unsigned r = (v.u + 0x7FFFu + ((v.u >> 16) & 1u)) >> 16;  // RNE
    return (short)r;
}
__device__ __forceinline__ float bf2f(short b) {
    union { float f; unsigned u; } v; v.u = ((unsigned)(unsigned short)b) << 16;
    return v.f;
}

// Kernel 1: h = x@W (fp32); emit hT (bf16, [D][N]), e_src, e_dst.
__global__ __launch_bounds__(256) void gat_prep(
    const float* __restrict__ x, const float* __restrict__ W,
    const float* __restrict__ a,
    short* __restrict__ hT, float* __restrict__ e_src, float* __restrict__ e_dst)
{
    __shared__ float x_s[32][260];          // +4 pad
    __shared__ float W_s[2][16][256];       // 16-row W chunk, double-buffered
    const int t  = threadIdx.x;
    const int ib = blockIdx.x * 32;

    #pragma unroll
    for (int rep = 0; rep < 8; ++rep) {
        int fi = rep * 256 + t;
        int r  = fi >> 6;
        int c4 = (fi & 63) * 4;
        float4 v = *(const float4*)(x + (size_t)(ib + r) * DD + c4);
        *(float4*)&x_s[r][c4] = v;
    }
    float4 wp[4];
    #pragma unroll
    for (int q = 0; q < 4; ++q) {
        int fi = q * 256 + t;
        wp[q] = *(const float4*)(W + (size_t)(fi >> 6) * DD + (fi & 63) * 4);
    }
    __syncthreads();

    const int il = t >> 3;
    const int dg = (t & 7) * 4;
    f32x4 acc[8];
    #pragma unroll
    for (int m = 0; m < 8; ++m) acc[m] = (f32x4){0.f, 0.f, 0.f, 0.f};

    for (int kc = 0; kc < 16; ++kc) {
        const int b = kc & 1;
        #pragma unroll
        for (int q = 0; q < 4; ++q) {
            int fi = q * 256 + t;
            *(float4*)&W_s[b][fi >> 6][(fi & 63) * 4] = wp[q];
        }
        if (kc < 15) {
            #pragma unroll
            for (int q = 0; q < 4; ++q) {
                int fi = q * 256 + t;
                wp[q] = *(const float4*)(W + (size_t)((kc + 1) * 16 + (fi >> 6)) * DD + (fi & 63) * 4);
            }
        }
        __syncthreads();
        #pragma unroll
        for (int kl = 0; kl < 16; ++kl) {
            float xv = x_s[il][kc * 16 + kl];
            #pragma unroll
            for (int m = 0; m < 8; ++m) {
                float4 wv = *(const float4*)&W_s[b][kl][m * 32 + dg];
                acc[m].x += xv * wv.x; acc[m].y += xv * wv.y;
                acc[m].z += xv * wv.z; acc[m].w += xv * wv.w;
            }
        }
    }

    const int ig = ib + il;
    float p1 = 0.f, p2 = 0.f;
    #pragma unroll
    for (int m = 0; m < 8; ++m) {
        #pragma unroll
        for (int j = 0; j < 4; ++j) {
            int col = m * 32 + dg + j;
            float hv = acc[m][j];
            p1 += hv * a[col];
            p2 += hv * a[DD + col];
            hT[(size_t)col * NN + ig] = f2bf(hv);
        }
    }
    p1 += __shfl_xor(p1, 1); p1 += __shfl_xor(p1, 2); p1 += __shfl_xor(p1, 4);
    p2 += __shfl_xor(p2, 1); p2 += __shfl_xor(p2, 2); p2 += __shfl_xor(p2, 4);
    if ((t & 7) == 0) { e_src[ig] = p1; e_dst[ig] = p2; }
}

// Kernel 2: fused masked softmax-numerator GEMM, j-split in 2 for 2 blocks/CU.
// Block (bid>>1, half=bid&1): rows [ibl,ibl+32), j in [half*4096, +4096).
// Writes partial numerator (half0 -> out buffer, half1 -> ws) + partial denom.
__global__ __launch_bounds__(512, 4) void gat_main(
    const int* __restrict__ adj, const short* __restrict__ hT,
    const float* __restrict__ e_src, const float* __restrict__ e_dst,
    float* __restrict__ num0, float* __restrict__ num1,
    float* __restrict__ den_part)
{
    __shared__ __align__(16) short B_s[2][256][40];   // hT panel, stride 40
    __shared__ __align__(16) short w_s[2][32][40];    // weight tile bf16

    const int t    = threadIdx.x;
    const int lane = t & 63;
    const int wid  = t >> 6;
    const int ibl  = (blockIdx.x >> 1) * 32;
    const int half = blockIdx.x & 1;
    const int jb   = half * JCH;

    const int irow = t >> 4;                  // 0..31
    const int jc2  = (t & 15) * 2;
    const float es = e_src[ibl + irow];
    const int* adj_row = adj + (size_t)(ibl + irow) * NN + jb;
    const short* hrow = hT + (size_t)(t >> 1) * NN + jb + (t & 1) * 16;
    const float* edp = e_dst + jb;

    const int ihalf = wid & 1;
    const int dbase = (wid >> 1) * 64;
    const int arow  = lane & 15;              // frag row (A) / col (B,D)
    const int kg8   = (lane >> 4) * 8;        // frag k-chunk

    float dsum = 0.f;
    f32x4 acc0 = {0.f,0.f,0.f,0.f}, acc1 = acc0, acc2 = acc0, acc3 = acc0;

    // 2-deep prefetch: set A = even steps, set B = odd steps
    int2   adA = *(const int2*)(adj_row + jc2);
    float2 edA = *(const float2*)(edp + jc2);
    int4   h0A = *(const int4*)(hrow);
    int4   h1A = *(const int4*)(hrow + 8);
    int2   adB = *(const int2*)(adj_row + 32 + jc2);
    float2 edB = *(const float2*)(edp + 32 + jc2);
    int4   h0B = *(const int4*)(hrow + 32);
    int4   h1B = *(const int4*)(hrow + 32 + 8);

#define MAIN_STEP(AD, ED, H0, H1, n)                                           \
    {                                                                          \
        const int c = (n) & 1;                                                 \
        float s0 = es + ED.x, s1 = es + ED.y;                                  \
        float l0 = s0 > 0.f ? s0 : 0.01f * s0;                                 \
        float l1 = s1 > 0.f ? s1 : 0.01f * s1;                                 \
        float w0 = AD.x > 0 ? __expf(l0) : 0.f;                                \
        float w1 = AD.y > 0 ? __expf(l1) : 0.f;                                \
        short b0 = f2bf(w0), b1 = f2bf(w1);                                    \
        dsum += bf2f(b0) + bf2f(b1);    /* denom = SAME bf16-rounded weights */\
        *(unsigned*)&w_s[c][irow][jc2] =                                       \
            (unsigned)(unsigned short)b0 | ((unsigned)(unsigned short)b1 << 16);\
        *(int4*)&B_s[c][t >> 1][(t & 1) * 16]     = H0;                        \
        *(int4*)&B_s[c][t >> 1][(t & 1) * 16 + 8] = H1;                        \
        int jn = (((n) + 2) & (NSTEP - 1)) * 32;    /* prefetch 2 ahead */     \
        AD = *(const int2*)(adj_row + jn + jc2);                               \
        ED = *(const float2*)(edp + jn + jc2);                                 \
        H0 = *(const int4*)(hrow + jn);                                        \
        H1 = *(const int4*)(hrow + jn + 8);                                    \
        __syncthreads();                 /* single barrier/step (dbuf LDS) */  \
        short8 af  = *(const short8*)&w_s[c][ihalf * 16 + arow][kg8];          \
        short8 bf0 = *(const short8*)&B_s[c][dbase +  0 + arow][kg8];          \
        short8 bf1 = *(const short8*)&B_s[c][dbase + 16 + arow][kg8];          \
        short8 bf2 = *(const short8*)&B_s[c][dbase + 32 + arow][kg8];          \
        short8 bf3 = *(const short8*)&B_s[c][dbase + 48 + arow][kg8];          \
        acc0 = __builtin_amdgcn_mfma_f32_16x16x32_bf16(af, bf0, acc0, 0, 0, 0);\
        acc1 = __builtin_amdgcn_mfma_f32_16x16x32_bf16(af, bf1, acc1, 0, 0, 0);\
        acc2 = __builtin_amdgcn_mfma_f32_16x16x32_bf16(af, bf2, acc2, 0, 0, 0);\
        acc3 = __builtin_amdgcn_mfma_f32_16x16x32_bf16(af, bf3, acc3, 0, 0, 0);\
    }

    for (int n = 0; n < NSTEP; n += 2) {
        MAIN_STEP(adA, edA, h0A, h1A, n)
        MAIN_STEP(adB, edB, h0B, h1B, n + 1)
    }
#undef MAIN_STEP

    // partial denom: 16 threads per row -> shfl tree, one writer per row
    dsum += __shfl_xor(dsum, 1);
    dsum += __shfl_xor(dsum, 2);
    dsum += __shfl_xor(dsum, 4);
    dsum += __shfl_xor(dsum, 8);
    if ((t & 15) == 0) den_part[half * NN + ibl + irow] = dsum;

    // write partial numerator (no div/elu here)
    float* num = half ? num1 : num0;
    const int rbase = ihalf * 16 + (lane >> 4) * 4;
    #pragma unroll
    for (int r = 0; r < 4; ++r) {
        size_t o = (size_t)(ibl + rbase + r) * DD + dbase + arow;
        num[o]      = acc0[r];
        num[o + 16] = acc1[r];
        num[o + 32] = acc2[r];
        num[o + 48] = acc3[r];
    }
}

// Kernel 3: out = elu((num0+num1) / (den0+den1)). num0 lives in d_out (in-place).
__global__ __launch_bounds__(256) void gat_epi(
    float* __restrict__ out, const float* __restrict__ num1,
    const float* __restrict__ den_part)
{
    int idx = blockIdx.x * 256 + threadIdx.x;       // float4 index; 64 per row
    int row = idx >> 6;
    float inv = 1.f / (den_part[row] + den_part[NN + row]);
    float4 p0 = ((const float4*)out)[idx];
    float4 p1 = ((const float4*)num1)[idx];
    float4 v;
    v.x = (p0.x + p1.x) * inv; v.x = v.x > 0.f ? v.x : expm1f(v.x);
    v.y = (p0.y + p1.y) * inv; v.y = v.y > 0.f ? v.y : expm1f(v.y);
    v.z = (p0.z + p1.z) * inv; v.z = v.z > 0.f ? v.z : expm1f(v.z);
    v.w = (p0.w + p1.w) * inv; v.w = v.w > 0.f ? v.w : expm1f(v.w);
    ((float4*)out)[idx] = v;
}

extern "C" void kernel_launch(void* const* d_in, const int* in_sizes, int n_in,
                              void* d_out, int out_size, void* d_ws, size_t ws_size,
                              hipStream_t stream) {
    const float* x   = (const float*)d_in[0];
    const int*   adj = (const int*)d_in[1];
    const float* W   = (const float*)d_in[2];
    const float* a   = (const float*)d_in[3];
    float* out = (float*)d_out;

    // ws layout: hT bf16 [256][8192] (4MB) | e_src | e_dst | den_part[2][NN] | num1 (8MB)
    char* w0 = (char*)d_ws;
    short* hT   = (short*)w0;
    float* esrc = (float*)(w0 + (size_t)DD * NN * 2);
    float* edst = esrc + NN;
    float* den  = edst + NN;
    float* num1 = den + 2 * NN;

    gat_prep<<<dim3(NN / 32), dim3(256), 0, stream>>>(x, W, a, hT, esrc, edst);
    gat_main<<<dim3((NN / 32) * JSPLIT), dim3(512), 0, stream>>>(
        adj, hT, esrc, edst, out, num1, den);
    gat_epi<<<dim3(NN * DD / 4 / 256), dim3(256), 0, stream>>>(out, num1, den);
}